// Round 5
// baseline (984.341 us; speedup 1.0000x reference)
//
#include <hip/hip_runtime.h>
#include <stdint.h>

#define NND 100000
#define HD  128
#define BB  512
#define DD  32
#define NNEG 5
#define CAP 12
#define ZROW 132
#define SENT 0xAAAAAAAAu

// ---------------- workspace layout (bytes) ----------------
#define OFF_WCNT     0                       // int[NND]
#define OFF_WSTEPS   400000                  // int[NND*CAP] packed s*64+slot
#define OFF_DEP      5200000                 // int[BB*38]
#define OFF_STEPOUT  5277824                 // float[BB*33*HD]

__global__ void build_writers(const int* __restrict__ u,
                              const int* __restrict__ nb,
                              int* __restrict__ wcnt,
                              int* __restrict__ wsteps) {
    int id = blockIdx.x * blockDim.x + threadIdx.x;
    if (id >= BB * 33) return;
    int s = id / 33, slot = id % 33;
    int row = (slot == 0) ? u[s] : nb[s * DD + slot - 1];
    int pos = atomicAdd(&wcnt[row], 1);
    if (pos < CAP) wsteps[row * CAP + pos] = s * 64 + slot;
}

__global__ void build_deps(const int* __restrict__ u,
                           const int* __restrict__ nb,
                           const int* __restrict__ neg,
                           const int* __restrict__ wcnt,
                           const int* __restrict__ wsteps,
                           int* __restrict__ dep) {
    int id = blockIdx.x * blockDim.x + threadIdx.x;
    if (id >= BB * 38) return;
    int t = id / 38, i = id % 38;
    int row = (i == 0) ? u[t] : (i < 33) ? nb[t * DD + i - 1]
                                         : neg[t * NNEG + i - 33];
    int lim = t * 64;
    int best = -1;
    int n = wcnt[row]; if (n > CAP) n = CAP;
    for (int p = 0; p < n; p++) {
        int e = wsteps[row * CAP + p];
        if (e < lim && e > best) best = e;   // max (step,slot) < t == numpy last-write-wins
    }
    dep[id] = best;
}

__device__ __forceinline__ uint32_t mall_load(const uint32_t* p) {
    return __hip_atomic_load(p, __ATOMIC_RELAXED, __HIP_MEMORY_SCOPE_AGENT);
}
__device__ __forceinline__ void mall_store2(float* p, float v0, float v1) {
    uint64_t pk = ((uint64_t)__float_as_uint(v1) << 32) | (uint64_t)__float_as_uint(v0);
    __hip_atomic_store((unsigned long long*)p, (unsigned long long)pk,
                       __ATOMIC_RELAXED, __HIP_MEMORY_SCOPE_AGENT);
}
__device__ __forceinline__ void flag_set(int* f) {
    __hip_atomic_store(f, 1, __ATOMIC_RELEASE, __HIP_MEMORY_SCOPE_WORKGROUP);
}
__device__ __forceinline__ int flag_peek(int* f) {
    return __hip_atomic_load(f, __ATOMIC_ACQUIRE, __HIP_MEMORY_SCOPE_WORKGROUP);
}
__device__ __forceinline__ void flag_wait(int* f) {
    while (!flag_peek(f)) __builtin_amdgcn_s_sleep(1);
}
__device__ __forceinline__ float sigf(float x) {
    return 1.f / (1.f + __expf(-x));
}

// 2-column dot: [1x128] (LDS, broadcast) @ W[:, c0:c0+2], 8-deep W prefetch.
__device__ __forceinline__ float2 dot_w2(const float* __restrict__ W, int c0,
                                         const float* __restrict__ zrow) {
    float a0 = 0.f, a1 = 0.f;
    float2 wb0[8], wb1[8];
    #pragma unroll
    for (int j = 0; j < 8; j++) wb0[j] = *(const float2*)&W[(size_t)j * HD + c0];
    #pragma unroll
    for (int kb = 0; kb < HD; kb += 16) {
        #pragma unroll
        for (int j = 0; j < 8; j++)
            wb1[j] = *(const float2*)&W[(size_t)(kb + 8 + j) * HD + c0];
        #pragma unroll
        for (int j = 0; j < 8; j++) {
            float z = zrow[kb + j];
            a0 = fmaf(z, wb0[j].x, a0); a1 = fmaf(z, wb0[j].y, a1);
        }
        if (kb + 16 < HD) {
            #pragma unroll
            for (int j = 0; j < 8; j++)
                wb0[j] = *(const float2*)&W[(size_t)(kb + 16 + j) * HD + c0];
        }
        #pragma unroll
        for (int j = 0; j < 8; j++) {
            float z = zrow[kb + 8 + j];
            a0 = fmaf(z, wb1[j].x, a0); a1 = fmaf(z, wb1[j].y, a1);
        }
    }
    return make_float2(a0, a1);
}

__global__ __launch_bounds__(512, 4)
void dyrep_main(const float* __restrict__ time_bar,
                const float* __restrict__ time_cur,
                const float* __restrict__ time_delta,
                const int* __restrict__ u,
                const int* __restrict__ nb,
                const int* __restrict__ neg,
                const float* __restrict__ z0,
                const float* __restrict__ W_omega, const float* __restrict__ b_omega,
                const float* __restrict__ W_h,     const float* __restrict__ b_h,
                const float* __restrict__ W_e2n,   const float* __restrict__ b_e2n,
                const float* __restrict__ W_rec_e, const float* __restrict__ b_rec_e,
                const float* __restrict__ W_rec_n, const float* __restrict__ b_rec_n,
                const float* __restrict__ W_time,  const float* __restrict__ b_time,
                const float* __restrict__ w_t_p,   const float* __restrict__ alpha_p,
                const float* __restrict__ psi_p,
                const int* __restrict__ dep,
                float* __restrict__ step_out,
                float* __restrict__ out) {
    __shared__ float zu[HD];
    __shared__ __align__(16) float znb[DD][ZROW];
    __shared__ float psum[8][HD];
    __shared__ float mbuf[HD];
    __shared__ int flag_zu;
    __shared__ int flag_ps[8];

    const int tid  = threadIdx.x;
    const int lane = tid & 63;
    const int wid  = tid >> 6;
    const int t    = blockIdx.x;
    const int c0   = lane * 2;

    if (tid == 0) flag_zu = 0;
    if (tid < 8)  flag_ps[tid] = 0;
    __syncthreads();

    // ---------- dep-independent preloads ----------
    const float tc  = time_cur[t];
    const float cb0 = b_e2n[c0]   + b_rec_n[c0]   + b_time[c0];
    const float cb1 = b_e2n[c0+1] + b_rec_n[c0+1] + b_time[c0+1];
    const float wt0 = W_time[c0], wt1 = W_time[c0+1];
    float td_r[4];
    #pragma unroll
    for (int r = 0; r < 4; r++)
        td_r[r] = tc - time_bar[(size_t)t * NND + (1 + 4*wid + r)];

    float cbu0=0.f, cbu1=0.f, td0=0.f, wo0=0.f, wo1=0.f, wt=0.f, al=0.f, ps=0.f, bom=0.f;
    float tdv[6];
    int   negdep[5]; const float* negsrc[5];
    if (wid == 0) {
        cbu0 = b_h[c0]   + b_rec_e[c0]   + b_time[c0];
        cbu1 = b_h[c0+1] + b_rec_e[c0+1] + b_time[c0+1];
        td0  = tc - time_bar[(size_t)t * NND + 0];
        wo0  = W_omega[c0]; wo1 = W_omega[c0+1];
        wt = *w_t_p; al = *alpha_p; ps = *psi_p; bom = *b_omega;
        tdv[0] = tc - time_delta[t * 2 + 0];
        #pragma unroll
        for (int d = 0; d < 5; d++) {
            int nn = neg[t * NNEG + d];
            tdv[1 + d] = tc - time_bar[(size_t)t * NND + nn];
            int dv = negdep[d] = dep[t * 38 + 33 + d];
            negsrc[d] = (dv >= 0)
                ? step_out + (size_t)(dv >> 6) * 33 * HD + (size_t)(dv & 63) * HD
                : z0 + (size_t)nn * HD;
        }
    }

    // ---------- resolve my two row-segments ----------
    // q=0 -> wave rows 0/1 (lanes 0-31 / 32-63); q=1 -> rows 2/3. c4 = lane&31.
    float* zflat = &znb[0][0];
    const uint32_t* pollp[2]; int lofs[2]; bool done[2];
    {
        #pragma unroll
        for (int q = 0; q < 2; q++) {
            int rl = q * 2 + (lane >> 5);
            int j  = 4 * wid + rl;
            int d  = dep[t * 38 + 1 + j];
            const float* sp = (d >= 0)
                ? step_out + (size_t)(d >> 6) * 33 * HD + (size_t)(d & 63) * HD
                : z0 + (size_t)nb[t * DD + j] * HD;
            sp += (lane & 31) * 4;
            lofs[q] = j * ZROW + (lane & 31) * 4;
            if (d >= 0) { pollp[q] = (const uint32_t*)sp; done[q] = false; }
            else { *(float4*)&zflat[lofs[q]] = *(const float4*)sp; done[q] = true;
                   pollp[q] = nullptr; }
        }
    }

    // ---------- wave 0: z_u segment (direct-stage if from z0) ----------
    const uint32_t* zup = nullptr;
    bool zu_seg_done = true;          // lanes >=32 and non-wave0: trivially done
    bool zu_staged = (wid != 0);      // wave0 tracks staging; others use the flag
    if (wid == 0) {
        int d = dep[t * 38 + 0];
        const float* src = (d >= 0)
            ? step_out + (size_t)(d >> 6) * 33 * HD + (size_t)(d & 63) * HD
            : z0 + (size_t)u[t] * HD;
        if (d < 0) {
            if (lane < 32) *(float4*)&zu[lane * 4] = *(const float4*)(src + lane * 4);
            __threadfence_block();
            if (lane == 0) flag_set(&flag_zu);
            zu_staged = true;
        } else {
            if (lane < 32) { zup = (const uint32_t*)(src + lane * 4); zu_seg_done = false; }
        }
    }
    __threadfence_block();   // direct-staged LDS rows visible before dots

    // ---------- event loop: stage / dot / publish rows in arrival order ----------
    float* my_out = step_out + (size_t)t * 33 * HD;
    float e0 = 0.f, e1 = 0.f;
    bool e2n_done = false;
    float2 racc[4];
    unsigned dotmask = 0, pubmask = 0;
    float s0 = 0.f, s1 = 0.f;        // psum accumulators

    while (pubmask != 0xFu) {
        bool progress = false;

        // wave 0: advance z_u staging
        if (!zu_staged) {
            if (!zu_seg_done) {
                uint32_t x0 = mall_load(zup+0), x1 = mall_load(zup+1);
                uint32_t x2 = mall_load(zup+2), x3 = mall_load(zup+3);
                if (x0 != SENT && x1 != SENT && x2 != SENT && x3 != SENT) {
                    *(float4*)&zu[lane * 4] =
                        make_float4(__uint_as_float(x0), __uint_as_float(x1),
                                    __uint_as_float(x2), __uint_as_float(x3));
                    zu_seg_done = true;
                }
            }
            __threadfence_block();
            unsigned long long bz = __ballot(zu_seg_done);
            if (bz == ~0ULL) {
                if (lane == 0) flag_set(&flag_zu);
                zu_staged = true;
                progress = true;
            }
        }

        // e2n slice the moment z_u is available
        if (!e2n_done && flag_peek(&flag_zu)) {
            float2 ee = dot_w2(W_e2n, c0, zu);
            e0 = ee.x; e1 = ee.y;
            e2n_done = true;
            progress = true;
        }

        // poll pending row segments
        #pragma unroll
        for (int q = 0; q < 2; q++) {
            if (!done[q]) {
                const uint32_t* ip = pollp[q];
                uint32_t x0 = mall_load(ip+0), x1 = mall_load(ip+1);
                uint32_t x2 = mall_load(ip+2), x3 = mall_load(ip+3);
                if (x0 != SENT && x1 != SENT && x2 != SENT && x3 != SENT) {
                    *(float4*)&zflat[lofs[q]] =
                        make_float4(__uint_as_float(x0), __uint_as_float(x1),
                                    __uint_as_float(x2), __uint_as_float(x3));
                    done[q] = true;
                }
            }
        }
        __threadfence_block();   // LDS writes drained before ballot/dot

        unsigned long long b0 = __ballot(done[0]);
        unsigned long long b1 = __ballot(done[1]);
        bool ready[4] = { (b0 & 0xFFFFFFFFull) == 0xFFFFFFFFull,
                          (b0 >> 32)           == 0xFFFFFFFFull,
                          (b1 & 0xFFFFFFFFull) == 0xFFFFFFFFull,
                          (b1 >> 32)           == 0xFFFFFFFFull };

        #pragma unroll
        for (int r = 0; r < 4; r++) {
            if (ready[r] && !((dotmask >> r) & 1u)) {
                const float* zr = &znb[4*wid + r][0];
                racc[r] = dot_w2(W_rec_n, c0, zr);
                float2 zz = *(const float2*)&zr[c0];
                s0 += zz.x; s1 += zz.y;
                dotmask |= 1u << r;
                progress = true;
            }
        }
        if (e2n_done) {
            unsigned todo = dotmask & ~pubmask;
            #pragma unroll
            for (int r = 0; r < 4; r++) {
                if ((todo >> r) & 1u) {
                    float p0 = racc[r].x + e0 + td_r[r] * wt0 + cb0;
                    float p1 = racc[r].y + e1 + td_r[r] * wt1 + cb1;
                    mall_store2(&my_out[(size_t)(1 + 4*wid + r) * HD + c0],
                                sigf(p0), sigf(p1));
                }
            }
            pubmask = dotmask;
        }
        if (!progress && pubmask != 0xFu) __builtin_amdgcn_s_sleep(1);
    }

    // ---------- psum publish ----------
    psum[wid][c0] = s0; psum[wid][c0+1] = s1;
    __threadfence_block();
    if (lane == 0) flag_set(&flag_ps[wid]);

    if (wid != 0) return;

    // ---------- wave 0: h_u ----------
    #pragma unroll
    for (int g = 0; g < 8; g++) flag_wait(&flag_ps[g]);
    {
        float m0 = 0.f, m1 = 0.f;
        #pragma unroll
        for (int g = 0; g < 8; g++) { m0 += psum[g][c0]; m1 += psum[g][c0+1]; }
        mbuf[c0] = m0 * (1.f/32.f); mbuf[c0+1] = m1 * (1.f/32.f);
    }
    __threadfence_block();
    {
        float2 ah = dot_w2(W_h, c0, mbuf);
        float2 ar = dot_w2(W_rec_e, c0, zu);
        float p0 = ah.x + ar.x + td0 * wt0 + cbu0;
        float p1 = ah.y + ar.y + td0 * wt1 + cbu1;
        mall_store2(&my_out[c0], sigf(p0), sigf(p1));
    }

    // ---------- wave 0: Hawkes lambdas (off the DAG critical path) ----------
    {
        float v = zu[c0] * wo0 + zu[c0+1] * wo1;
        #pragma unroll
        for (int off = 32; off; off >>= 1) v += __shfl_down(v, off);
        if (lane == 0) {
            float g = v + bom + al * __expf(-wt * tdv[0]);
            float x = g / ps;
            out[t] = ps * (fmaxf(x, 0.f) + log1pf(__expf(-fabsf(x))));
        }
        for (int d = 0; d < 5; d++) {
            const float* sp = negsrc[d] + c0;
            float x0, x1;
            if (negdep[d] >= 0) {
                const uint32_t* ip = (const uint32_t*)sp;
                uint32_t a, b;
                while (true) {
                    a = mall_load(ip + 0); b = mall_load(ip + 1);
                    if (a != SENT && b != SENT) break;
                    __builtin_amdgcn_s_sleep(1);
                }
                x0 = __uint_as_float(a); x1 = __uint_as_float(b);
            } else {
                x0 = sp[0]; x1 = sp[1];
            }
            float v2 = x0 * wo0 + x1 * wo1;
            #pragma unroll
            for (int off = 32; off; off >>= 1) v2 += __shfl_down(v2, off);
            if (lane == 0) {
                float g = v2 + bom + al * __expf(-wt * tdv[1 + d]);
                float x = g / ps;
                out[BB + t * NNEG + d] =
                    ps * (fmaxf(x, 0.f) + log1pf(__expf(-fabsf(x)))) * (1.0f / NNEG);
            }
        }
    }
}

extern "C" void kernel_launch(void* const* d_in, const int* in_sizes, int n_in,
                              void* d_out, int out_size, void* d_ws, size_t ws_size,
                              hipStream_t stream) {
    const float* time_bar  = (const float*)d_in[0];
    const float* time_cur  = (const float*)d_in[1];
    const float* time_delta= (const float*)d_in[2];
    const int*   u         = (const int*)d_in[3];
    const int*   nb        = (const int*)d_in[4];
    const int*   neg       = (const int*)d_in[5];
    const float* z0        = (const float*)d_in[6];
    const float* W_omega   = (const float*)d_in[7];
    const float* b_omega   = (const float*)d_in[8];
    const float* W_h       = (const float*)d_in[9];
    const float* b_h       = (const float*)d_in[10];
    const float* W_e2n     = (const float*)d_in[11];
    const float* b_e2n     = (const float*)d_in[12];
    const float* W_rec_e   = (const float*)d_in[13];
    const float* b_rec_e   = (const float*)d_in[14];
    const float* W_rec_n   = (const float*)d_in[15];
    const float* b_rec_n   = (const float*)d_in[16];
    const float* W_time    = (const float*)d_in[17];
    const float* b_time    = (const float*)d_in[18];
    const float* w_t       = (const float*)d_in[19];
    const float* alpha     = (const float*)d_in[20];
    const float* psi       = (const float*)d_in[21];

    char* ws = (char*)d_ws;
    int*   wcnt     = (int*)(ws + OFF_WCNT);
    int*   wsteps   = (int*)(ws + OFF_WSTEPS);
    int*   dep      = (int*)(ws + OFF_DEP);
    float* step_out = (float*)(ws + OFF_STEPOUT);
    float* out      = (float*)d_out;

    hipMemsetAsync(ws + OFF_WCNT, 0, NND * 4, stream);
    hipMemsetAsync(ws + OFF_STEPOUT, 0xAA, (size_t)BB * 33 * HD * 4, stream);
    build_writers<<<(BB * 33 + 255) / 256, 256, 0, stream>>>(u, nb, wcnt, wsteps);
    build_deps<<<(BB * 38 + 255) / 256, 256, 0, stream>>>(u, nb, neg, wcnt, wsteps, dep);
    dyrep_main<<<BB, 512, 0, stream>>>(time_bar, time_cur, time_delta, u, nb, neg, z0,
                                       W_omega, b_omega, W_h, b_h, W_e2n, b_e2n,
                                       W_rec_e, b_rec_e, W_rec_n, b_rec_n,
                                       W_time, b_time, w_t, alpha, psi,
                                       dep, step_out, out);
}

// Round 6
// 391.514 us; speedup vs baseline: 2.5142x; 2.5142x over previous
//
#include <hip/hip_runtime.h>
#include <stdint.h>

#define NND 100000
#define HD  128
#define BB  512
#define DD  32
#define NNEG 5
#define CAP 12
#define ZROW 132
#define SENT 0xAAAAAAAAu

// ---------------- workspace layout (bytes) ----------------
#define OFF_WCNT     0                       // int[NND]
#define OFF_WSTEPS   400000                  // int[NND*CAP] packed s*64+slot
#define OFF_DEP      5200000                 // int[BB*38]
#define OFF_STEPOUT  5277824                 // float[BB*33*HD]

__global__ void build_writers(const int* __restrict__ u,
                              const int* __restrict__ nb,
                              int* __restrict__ wcnt,
                              int* __restrict__ wsteps) {
    int id = blockIdx.x * blockDim.x + threadIdx.x;
    if (id >= BB * 33) return;
    int s = id / 33, slot = id % 33;
    int row = (slot == 0) ? u[s] : nb[s * DD + slot - 1];
    int pos = atomicAdd(&wcnt[row], 1);
    if (pos < CAP) wsteps[row * CAP + pos] = s * 64 + slot;
}

__global__ void build_deps(const int* __restrict__ u,
                           const int* __restrict__ nb,
                           const int* __restrict__ neg,
                           const int* __restrict__ wcnt,
                           const int* __restrict__ wsteps,
                           int* __restrict__ dep) {
    int id = blockIdx.x * blockDim.x + threadIdx.x;
    if (id >= BB * 38) return;
    int t = id / 38, i = id % 38;
    int row = (i == 0) ? u[t] : (i < 33) ? nb[t * DD + i - 1]
                                         : neg[t * NNEG + i - 33];
    int lim = t * 64;
    int best = -1;
    int n = wcnt[row]; if (n > CAP) n = CAP;
    for (int p = 0; p < n; p++) {
        int e = wsteps[row * CAP + p];
        if (e < lim && e > best) best = e;   // max (step,slot) < t == numpy last-write-wins
    }
    dep[id] = best;
}

__device__ __forceinline__ uint32_t mall_load(const uint32_t* p) {
    return __hip_atomic_load(p, __ATOMIC_RELAXED, __HIP_MEMORY_SCOPE_AGENT);
}
__device__ __forceinline__ void mall_store2(float* p, float v0, float v1) {
    uint64_t pk = ((uint64_t)__float_as_uint(v1) << 32) | (uint64_t)__float_as_uint(v0);
    __hip_atomic_store((unsigned long long*)p, (unsigned long long)pk,
                       __ATOMIC_RELAXED, __HIP_MEMORY_SCOPE_AGENT);
}
__device__ __forceinline__ void flag_set(int* f) {
    __hip_atomic_store(f, 1, __ATOMIC_RELEASE, __HIP_MEMORY_SCOPE_WORKGROUP);
}
__device__ __forceinline__ int flag_peek(int* f) {
    return __hip_atomic_load(f, __ATOMIC_ACQUIRE, __HIP_MEMORY_SCOPE_WORKGROUP);
}
__device__ __forceinline__ void flag_wait(int* f) {
    while (!flag_peek(f)) __builtin_amdgcn_s_sleep(1);
}
__device__ __forceinline__ float sigf(float x) {
    return 1.f / (1.f + __expf(-x));
}

// 2-column dot: [1x128] (LDS, broadcast) @ W[:, c0:c0+2], 8-deep W prefetch.
__device__ __forceinline__ float2 dot_w2(const float* __restrict__ W, int c0,
                                         const float* __restrict__ zrow) {
    float a0 = 0.f, a1 = 0.f;
    float2 wb0[8], wb1[8];
    #pragma unroll
    for (int j = 0; j < 8; j++) wb0[j] = *(const float2*)&W[(size_t)j * HD + c0];
    #pragma unroll
    for (int kb = 0; kb < HD; kb += 16) {
        #pragma unroll
        for (int j = 0; j < 8; j++)
            wb1[j] = *(const float2*)&W[(size_t)(kb + 8 + j) * HD + c0];
        #pragma unroll
        for (int j = 0; j < 8; j++) {
            float z = zrow[kb + j];
            a0 = fmaf(z, wb0[j].x, a0); a1 = fmaf(z, wb0[j].y, a1);
        }
        if (kb + 16 < HD) {
            #pragma unroll
            for (int j = 0; j < 8; j++)
                wb0[j] = *(const float2*)&W[(size_t)(kb + 16 + j) * HD + c0];
        }
        #pragma unroll
        for (int j = 0; j < 8; j++) {
            float z = zrow[kb + 8 + j];
            a0 = fmaf(z, wb1[j].x, a0); a1 = fmaf(z, wb1[j].y, a1);
        }
    }
    return make_float2(a0, a1);
}

__global__ __launch_bounds__(512, 4)
void dyrep_main(const float* __restrict__ time_bar,
                const float* __restrict__ time_cur,
                const float* __restrict__ time_delta,
                const int* __restrict__ u,
                const int* __restrict__ nb,
                const int* __restrict__ neg,
                const float* __restrict__ z0,
                const float* __restrict__ W_omega, const float* __restrict__ b_omega,
                const float* __restrict__ W_h,     const float* __restrict__ b_h,
                const float* __restrict__ W_e2n,   const float* __restrict__ b_e2n,
                const float* __restrict__ W_rec_e, const float* __restrict__ b_rec_e,
                const float* __restrict__ W_rec_n, const float* __restrict__ b_rec_n,
                const float* __restrict__ W_time,  const float* __restrict__ b_time,
                const float* __restrict__ w_t_p,   const float* __restrict__ alpha_p,
                const float* __restrict__ psi_p,
                const int* __restrict__ dep,
                float* __restrict__ step_out,
                float* __restrict__ out) {
    __shared__ float zu[HD];
    __shared__ __align__(16) float znb[DD][ZROW];
    __shared__ float psum[8][HD];
    __shared__ float mbuf[HD];
    __shared__ int flag_zu;
    __shared__ int flag_ps[8];

    const int tid  = threadIdx.x;
    const int lane = tid & 63;
    const int wid  = tid >> 6;
    const int t    = blockIdx.x;
    const int c0   = lane * 2;          // this lane's two output columns

    if (tid == 0) flag_zu = 0;
    if (tid < 8)  flag_ps[tid] = 0;
    __syncthreads();

    // ---------- per-wave dep-independent preloads ----------
    const float tc  = time_cur[t];
    const float cb0 = b_e2n[c0] + b_rec_n[c0] + b_time[c0];
    const float cb1 = b_e2n[c0+1] + b_rec_n[c0+1] + b_time[c0+1];
    const float wt0 = W_time[c0], wt1 = W_time[c0+1];
    float td_r[4];
    #pragma unroll
    for (int r = 0; r < 4; r++)
        td_r[r] = tc - time_bar[(size_t)t * NND + (1 + 4*wid + r)];

    // wave-0 extras
    float cbu0=0.f, cbu1=0.f, td0=0.f, wo0=0.f, wo1=0.f, wt=0.f, al=0.f, ps=0.f, bom=0.f;
    float tdv[6];
    int   negdep[5]; const float* negsrc[5];
    if (wid == 0) {
        cbu0 = b_h[c0] + b_rec_e[c0] + b_time[c0];
        cbu1 = b_h[c0+1] + b_rec_e[c0+1] + b_time[c0+1];
        td0  = tc - time_bar[(size_t)t * NND + 0];
        wo0  = W_omega[c0]; wo1 = W_omega[c0+1];
        wt = *w_t_p; al = *alpha_p; ps = *psi_p; bom = *b_omega;
        tdv[0] = tc - time_delta[t * 2 + 0];
        #pragma unroll
        for (int d = 0; d < 5; d++) {
            int nn = neg[t * NNEG + d];
            tdv[1 + d] = tc - time_bar[(size_t)t * NND + nn];
            int dv = negdep[d] = dep[t * 38 + 33 + d];
            negsrc[d] = (dv >= 0)
                ? step_out + (size_t)(dv >> 6) * 33 * HD + (size_t)(dv & 63) * HD
                : z0 + (size_t)nn * HD;
        }
    }

    // ---------- wave 0: stage z_u (gates every wave's epilogue) ----------
    if (wid == 0) {
        int d = dep[t * 38 + 0];
        const float* src = (d >= 0)
            ? step_out + (size_t)(d >> 6) * 33 * HD + (size_t)(d & 63) * HD
            : z0 + (size_t)u[t] * HD;
        if (lane < 32) {
            const float* sp = src + lane * 4;
            float4 v;
            if (d >= 0) {
                const uint32_t* ip = (const uint32_t*)sp;
                uint32_t x0, x1, x2, x3;
                while (true) {
                    x0 = mall_load(ip+0); x1 = mall_load(ip+1);
                    x2 = mall_load(ip+2); x3 = mall_load(ip+3);
                    if (x0 != SENT && x1 != SENT && x2 != SENT && x3 != SENT) break;
                    __builtin_amdgcn_s_sleep(1);
                }
                v = make_float4(__uint_as_float(x0), __uint_as_float(x1),
                                __uint_as_float(x2), __uint_as_float(x3));
            } else {
                v = *(const float4*)sp;
            }
            *(float4*)&zu[lane * 4] = v;
        }
        __threadfence_block();
        if (lane == 0) flag_set(&flag_zu);
    }

    // ---------- stage this wave's 4 neighbor rows (poll = wait) ----------
    {
        const uint32_t* pollp[2]; int lofs[2]; float4 direct[2];
        unsigned pend = 0;
        #pragma unroll
        for (int q = 0; q < 2; q++) {
            int idx = lane + q * 64;
            int rl = idx >> 5, c4 = idx & 31;
            int j = 4 * wid + rl;
            int d = dep[t * 38 + 1 + j];
            const float* sp = (d >= 0)
                ? step_out + (size_t)(d >> 6) * 33 * HD + (size_t)(d & 63) * HD
                : z0 + (size_t)nb[t * DD + j] * HD;
            sp += c4 * 4;
            lofs[q] = j * ZROW + c4 * 4;
            if (d >= 0) { pollp[q] = (const uint32_t*)sp; pend |= (1u << q); }
            else direct[q] = *(const float4*)sp;
        }
        float* zflat = &znb[0][0];
        #pragma unroll
        for (int q = 0; q < 2; q++)
            if (!((pend >> q) & 1)) *(float4*)&zflat[lofs[q]] = direct[q];
        while (__ballot(pend != 0) != 0ULL) {
            #pragma unroll
            for (int q = 0; q < 2; q++) {
                if ((pend >> q) & 1) {
                    const uint32_t* ip = pollp[q];
                    uint32_t x0 = mall_load(ip+0), x1 = mall_load(ip+1);
                    uint32_t x2 = mall_load(ip+2), x3 = mall_load(ip+3);
                    if (x0 != SENT && x1 != SENT && x2 != SENT && x3 != SENT) {
                        *(float4*)&zflat[lofs[q]] =
                            make_float4(__uint_as_float(x0), __uint_as_float(x1),
                                        __uint_as_float(x2), __uint_as_float(x3));
                        pend &= ~(1u << q);
                    }
                }
            }
            if (pend) __builtin_amdgcn_s_sleep(1);
        }
    }
    __threadfence_block();   // own-wave LDS writes visible before reads

    // ---------- psum (column sums of my 4 rows) + release ----------
    {
        float s0 = 0.f, s1 = 0.f;
        #pragma unroll
        for (int r = 0; r < 4; r++) {
            float2 zz = *(const float2*)&znb[4*wid + r][c0];
            s0 += zz.x; s1 += zz.y;
        }
        psum[wid][c0] = s0; psum[wid][c0+1] = s1;
        if (lane == 0) flag_set(&flag_ps[wid]);   // release waits lgkmcnt(0)
    }

    // ---------- e2n slice EARLY if z_u is already staged (z0 case, ~90%) ----------
    float e0 = 0.f, e1 = 0.f;
    bool e2n_done = false;
    if (flag_peek(&flag_zu)) {
        float2 ee = dot_w2(W_e2n, c0, zu);
        e0 = ee.x; e1 = ee.y;
        e2n_done = true;
    }

    // ---------- 4x128 @ 128x128 GEMM (2 cols/lane), ping-pong prefetch ----------
    float2 acc[4];
    #pragma unroll
    for (int r = 0; r < 4; r++) { acc[r].x = 0.f; acc[r].y = 0.f; }
    {
        const float* zr[4];
        #pragma unroll
        for (int r = 0; r < 4; r++) zr[r] = &znb[4*wid + r][0];
        float4 zA[4], zB[4]; float2 wA[4], wB[4];
        #pragma unroll
        for (int r = 0; r < 4; r++) zA[r] = *(const float4*)&zr[r][0];
        #pragma unroll
        for (int kk = 0; kk < 4; kk++) wA[kk] = *(const float2*)&W_rec_n[(size_t)kk * HD + c0];
        for (int kb = 0; kb < HD; kb += 8) {
            #pragma unroll
            for (int r = 0; r < 4; r++) zB[r] = *(const float4*)&zr[r][kb + 4];
            #pragma unroll
            for (int kk = 0; kk < 4; kk++)
                wB[kk] = *(const float2*)&W_rec_n[(size_t)(kb + 4 + kk) * HD + c0];
            #pragma unroll
            for (int r = 0; r < 4; r++) {
                const float za[4] = {zA[r].x, zA[r].y, zA[r].z, zA[r].w};
                #pragma unroll
                for (int kk = 0; kk < 4; kk++) {
                    acc[r].x = fmaf(za[kk], wA[kk].x, acc[r].x);
                    acc[r].y = fmaf(za[kk], wA[kk].y, acc[r].y);
                }
            }
            if (kb + 8 < HD) {
                #pragma unroll
                for (int r = 0; r < 4; r++) zA[r] = *(const float4*)&zr[r][kb + 8];
                #pragma unroll
                for (int kk = 0; kk < 4; kk++)
                    wA[kk] = *(const float2*)&W_rec_n[(size_t)(kb + 8 + kk) * HD + c0];
            }
            #pragma unroll
            for (int r = 0; r < 4; r++) {
                const float zb[4] = {zB[r].x, zB[r].y, zB[r].z, zB[r].w};
                #pragma unroll
                for (int kk = 0; kk < 4; kk++) {
                    acc[r].x = fmaf(zb[kk], wB[kk].x, acc[r].x);
                    acc[r].y = fmaf(zb[kk], wB[kk].y, acc[r].y);
                }
            }
        }
    }

    // ---------- e2n late path (z_u was not staged when we checked) ----------
    if (!e2n_done) {
        flag_wait(&flag_zu);
        float2 ee = dot_w2(W_e2n, c0, zu);
        e0 = ee.x; e1 = ee.y;
    }

    // ---------- publish my 4 rows ----------
    float* my_out = step_out + (size_t)t * 33 * HD;
    #pragma unroll
    for (int r = 0; r < 4; r++) {
        int j = 4 * wid + r;
        float p0 = acc[r].x + e0 + td_r[r] * wt0 + cb0;
        float p1 = acc[r].y + e1 + td_r[r] * wt1 + cb1;
        mall_store2(&my_out[(size_t)(1 + j) * HD + c0], sigf(p0), sigf(p1));
    }

    if (wid != 0) return;

    // ---------- wave 0: h_u = sigmoid(mean@W_h + z_u@W_rec_e + ...) ----------
    #pragma unroll
    for (int g = 0; g < 8; g++) flag_wait(&flag_ps[g]);
    {
        float m0 = 0.f, m1 = 0.f;
        #pragma unroll
        for (int g = 0; g < 8; g++) { m0 += psum[g][c0]; m1 += psum[g][c0+1]; }
        mbuf[c0] = m0 * (1.f/32.f); mbuf[c0+1] = m1 * (1.f/32.f);
    }
    __threadfence_block();
    {
        float a0 = 0.f, a1 = 0.f;
        for (int kb = 0; kb < HD; kb += 4) {
            float4 mv = *(const float4*)&mbuf[kb];
            float4 zv = *(const float4*)&zu[kb];
            const float mm[4] = {mv.x, mv.y, mv.z, mv.w};
            const float zz[4] = {zv.x, zv.y, zv.z, zv.w};
            #pragma unroll
            for (int kk = 0; kk < 4; kk++) {
                float2 wh = *(const float2*)&W_h[(size_t)(kb + kk) * HD + c0];
                float2 wr = *(const float2*)&W_rec_e[(size_t)(kb + kk) * HD + c0];
                a0 = fmaf(mm[kk], wh.x, fmaf(zz[kk], wr.x, a0));
                a1 = fmaf(mm[kk], wh.y, fmaf(zz[kk], wr.y, a1));
            }
        }
        float p0 = a0 + td0 * wt0 + cbu0;
        float p1 = a1 + td0 * wt1 + cbu1;
        mall_store2(&my_out[c0], sigf(p0), sigf(p1));
    }

    // ---------- wave 0: Hawkes lambdas (off the DAG critical path) ----------
    {
        float v = zu[c0] * wo0 + zu[c0+1] * wo1;
        #pragma unroll
        for (int off = 32; off; off >>= 1) v += __shfl_down(v, off);
        if (lane == 0) {
            float g = v + bom + al * __expf(-wt * tdv[0]);
            float x = g / ps;
            out[t] = ps * (fmaxf(x, 0.f) + log1pf(__expf(-fabsf(x))));
        }
        for (int d = 0; d < 5; d++) {
            const float* sp = negsrc[d] + c0;
            float x0, x1;
            if (negdep[d] >= 0) {
                const uint32_t* ip = (const uint32_t*)sp;
                uint32_t a, b;
                while (true) {
                    a = mall_load(ip + 0); b = mall_load(ip + 1);
                    if (a != SENT && b != SENT) break;
                    __builtin_amdgcn_s_sleep(1);
                }
                x0 = __uint_as_float(a); x1 = __uint_as_float(b);
            } else {
                x0 = sp[0]; x1 = sp[1];
            }
            float v2 = x0 * wo0 + x1 * wo1;
            #pragma unroll
            for (int off = 32; off; off >>= 1) v2 += __shfl_down(v2, off);
            if (lane == 0) {
                float g = v2 + bom + al * __expf(-wt * tdv[1 + d]);
                float x = g / ps;
                out[BB + t * NNEG + d] =
                    ps * (fmaxf(x, 0.f) + log1pf(__expf(-fabsf(x)))) * (1.0f / NNEG);
            }
        }
    }
}

extern "C" void kernel_launch(void* const* d_in, const int* in_sizes, int n_in,
                              void* d_out, int out_size, void* d_ws, size_t ws_size,
                              hipStream_t stream) {
    const float* time_bar  = (const float*)d_in[0];
    const float* time_cur  = (const float*)d_in[1];
    const float* time_delta= (const float*)d_in[2];
    const int*   u         = (const int*)d_in[3];
    const int*   nb        = (const int*)d_in[4];
    const int*   neg       = (const int*)d_in[5];
    const float* z0        = (const float*)d_in[6];
    const float* W_omega   = (const float*)d_in[7];
    const float* b_omega   = (const float*)d_in[8];
    const float* W_h       = (const float*)d_in[9];
    const float* b_h       = (const float*)d_in[10];
    const float* W_e2n     = (const float*)d_in[11];
    const float* b_e2n     = (const float*)d_in[12];
    const float* W_rec_e   = (const float*)d_in[13];
    const float* b_rec_e   = (const float*)d_in[14];
    const float* W_rec_n   = (const float*)d_in[15];
    const float* b_rec_n   = (const float*)d_in[16];
    const float* W_time    = (const float*)d_in[17];
    const float* b_time    = (const float*)d_in[18];
    const float* w_t       = (const float*)d_in[19];
    const float* alpha     = (const float*)d_in[20];
    const float* psi       = (const float*)d_in[21];

    char* ws = (char*)d_ws;
    int*   wcnt     = (int*)(ws + OFF_WCNT);
    int*   wsteps   = (int*)(ws + OFF_WSTEPS);
    int*   dep      = (int*)(ws + OFF_DEP);
    float* step_out = (float*)(ws + OFF_STEPOUT);
    float* out      = (float*)d_out;

    hipMemsetAsync(ws + OFF_WCNT, 0, NND * 4, stream);
    hipMemsetAsync(ws + OFF_STEPOUT, 0xAA, (size_t)BB * 33 * HD * 4, stream);
    build_writers<<<(BB * 33 + 255) / 256, 256, 0, stream>>>(u, nb, wcnt, wsteps);
    build_deps<<<(BB * 38 + 255) / 256, 256, 0, stream>>>(u, nb, neg, wcnt, wsteps, dep);
    dyrep_main<<<BB, 512, 0, stream>>>(time_bar, time_cur, time_delta, u, nb, neg, z0,
                                       W_omega, b_omega, W_h, b_h, W_e2n, b_e2n,
                                       W_rec_e, b_rec_e, W_rec_n, b_rec_n,
                                       W_time, b_time, w_t, alpha, psi,
                                       dep, step_out, out);
}